// Round 1
// baseline (12521.597 us; speedup 1.0000x reference)
//
#include <hip/hip_runtime.h>

#define TT 1024
#define BB 128
#define HH 512

typedef __bf16  bf16x8 __attribute__((ext_vector_type(8)));
typedef float   f32x4  __attribute__((ext_vector_type(4)));
typedef float   f32x8  __attribute__((ext_vector_type(8)));
typedef unsigned long long u64;
typedef u64     u64x2  __attribute__((ext_vector_type(2)));

// Convert 8 contiguous fp32 -> 8 bf16 (RNE via hardware cvt).
static __device__ __forceinline__ bf16x8 cvt8(const float* __restrict__ p) {
  f32x8 f = *(const f32x8*)p;
  return __builtin_convertvector(f, bf16x8);
}

// Zero h double-buffer (2*128*512 bf16 = 65536 uints) + counters (256 uints).
// Launched with exactly 257*256 = 65792 threads.
__global__ void lstm_init(unsigned int* __restrict__ buf) {
  buf[blockIdx.x * 256u + threadIdx.x] = 0u;
}

// Persistent LSTM kernel.
// 256 WGs = 8 batch-groups (16 rows) x 32 hidden-slices (16 units).
// 256 threads = 4 waves; wave w owns gate region w (i,f,o,g) x 16 cols.
__global__ __launch_bounds__(256, 1) void lstm_persist(
    const float* __restrict__ x,      // (T,B,512) fp32
    const float* __restrict__ W_ih,   // (2048,512) fp32
    const float* __restrict__ b_ih,   // (2048)
    const float* __restrict__ W_hh,   // (2048,512) fp32
    const float* __restrict__ b_hh,   // (2048)
    float* __restrict__ out,          // T*B*H output ++ h ++ c
    unsigned short* __restrict__ h_buf,   // ws: 2 x 128x512 bf16
    unsigned int* __restrict__ counters)  // ws: 8 groups x 32 uints (128B stride)
{
  const int wg   = blockIdx.x;
  const int bg   = wg & 7;        // batch group (also ~XCD under round-robin, perf-only)
  const int ng   = wg >> 3;       // hidden slice 0..31
  const int rowbase = bg << 4;    // batch row base
  const int hbase   = ng << 4;    // hidden unit base
  const int tid  = threadIdx.x;
  const int wave = tid >> 6;      // gate region: 0=i 1=f 2=o 3=g
  const int lane = tid & 63;
  const int fr   = lane & 15;           // fragment row (A.m) / col (B.n)
  const int kl   = (lane >> 4) << 3;    // k offset within 32-chunk

  __shared__ __align__(16) unsigned char hsm[16384];  // staged h tile 16x512 bf16 (swizzled)
  __shared__ float zbuf[4][16][16];                   // z exchange i/f/o/g

  // ---- load weight B-fragments into registers (once) ----
  bf16x8 Bx[16], Bh[16];
  const int gcol = (wave << 9) + hbase + fr;    // 0..2047
  {
    const float* wi = W_ih + (size_t)gcol * 512 + kl;
    const float* wh = W_hh + (size_t)gcol * 512 + kl;
#pragma unroll
    for (int kk = 0; kk < 16; ++kk) {
      Bx[kk] = cvt8(wi + kk * 32);
      Bh[kk] = cvt8(wh + kk * 32);
    }
  }
  const float bias_l = b_ih[gcol] + b_hh[gcol];

  unsigned int* cnt = counters + (bg << 5);
  const int er = tid >> 4;    // epilogue row 0..15
  const int eu = tid & 15;    // epilogue unit 0..15
  const int arow = rowbase + fr;

  float c_reg = 0.f;
  float h_last = 0.f;

#pragma clang loop unroll(disable)
  for (int t = 0; t < TT; ++t) {
    f32x4 acc0 = {0.f,0.f,0.f,0.f}, acc1 = {0.f,0.f,0.f,0.f};
    f32x4 acc2 = {0.f,0.f,0.f,0.f}, acc3 = {0.f,0.f,0.f,0.f};

    // ---- x-part: independent of h_{t-1}; hides under the spin below ----
    {
      const float* xp = x + ((size_t)t * BB + arow) * 512 + kl;
      bf16x8 ax[16];
#pragma unroll
      for (int kk = 0; kk < 16; ++kk) ax[kk] = cvt8(xp + kk * 32);
#pragma unroll
      for (int kk = 0; kk < 16; ++kk) {
        if (kk & 1) acc1 = __builtin_amdgcn_mfma_f32_16x16x32_bf16(ax[kk], Bx[kk], acc1, 0, 0, 0);
        else        acc0 = __builtin_amdgcn_mfma_f32_16x16x32_bf16(ax[kk], Bx[kk], acc0, 0, 0, 0);
      }
    }

    // ---- wait until all 32 WGs of this group published h_{t-1} ----
    if (t > 0) {
      if (tid == 0) {
        const unsigned int target = (unsigned int)t << 5;   // 32*t
        while (__hip_atomic_load(cnt, __ATOMIC_RELAXED, __HIP_MEMORY_SCOPE_AGENT) < target) { }
      }
      __syncthreads();
      __builtin_amdgcn_fence(__ATOMIC_ACQUIRE, "workgroup");
    }

    // ---- stage h_{t-1} tile (16 rows x 512) into LDS via device-scope loads ----
    {
      const int r  = tid >> 4;
      const int j0 = tid & 15;
      u64* hq = (u64*)(h_buf + (size_t)(t & 1) * (BB * HH) + (size_t)(rowbase + r) * HH);
#pragma unroll
      for (int i = 0; i < 8; ++i) {
        const int j = j0 + (i << 4);                 // u64 index in row, 0..127
        u64 q = __hip_atomic_load(hq + j, __ATOMIC_RELAXED, __HIP_MEMORY_SCOPE_AGENT);
        int byte = (r << 10) + (j << 3);
        byte ^= (r & 7) << 4;                        // XOR swizzle vs 16-lane bank conflict
        *(u64*)(hsm + byte) = q;
      }
    }
    __syncthreads();

    // ---- h-part MFMAs from LDS ----
#pragma unroll
    for (int kk = 0; kk < 16; ++kk) {
      int byte = (fr << 10) + ((kk * 32 + kl) << 1);
      byte ^= (fr & 7) << 4;
      bf16x8 a = *(const bf16x8*)(hsm + byte);
      if (kk & 1) acc3 = __builtin_amdgcn_mfma_f32_16x16x32_bf16(a, Bh[kk], acc3, 0, 0, 0);
      else        acc2 = __builtin_amdgcn_mfma_f32_16x16x32_bf16(a, Bh[kk], acc2, 0, 0, 0);
    }

    // ---- z -> LDS (C/D layout: col = lane&15, row = (lane>>4)*4 + reg) ----
    {
      f32x4 z = acc0 + acc1 + acc2 + acc3;
      const int r0 = (lane >> 4) << 2;
#pragma unroll
      for (int r = 0; r < 4; ++r) zbuf[wave][r0 + r][fr] = z[r] + bias_l;
    }
    __syncthreads();

    // ---- gates + state update; each thread owns one (row, unit) ----
    {
      const float iz = zbuf[0][er][eu];
      const float fz = zbuf[1][er][eu];
      const float oz = zbuf[2][er][eu];
      const float gz = zbuf[3][er][eu];
      const float ig = 1.f / (1.f + __expf(-iz));
      const float fg = 1.f / (1.f + __expf(-fz));
      const float og = 1.f / (1.f + __expf(-oz));
      const float e2g = __expf(2.f * gz);
      const float gg = 1.f - 2.f / (e2g + 1.f);      // tanh(gz)
      c_reg = fg * c_reg + ig * gg;
      const float e2c = __expf(2.f * c_reg);
      const float tc = 1.f - 2.f / (e2c + 1.f);      // tanh(c)
      h_last = og * tc;

      // publishable bf16 h (device-scope store, bypasses L1/L2)
      const unsigned short hv = __builtin_bit_cast(unsigned short, (__bf16)h_last);
      __hip_atomic_store(h_buf + (size_t)((t + 1) & 1) * (BB * HH)
                               + (size_t)(rowbase + er) * HH + (hbase + eu),
                         hv, __ATOMIC_RELAXED, __HIP_MEMORY_SCOPE_AGENT);
      // fp32 output
      out[(size_t)t * (BB * HH) + (size_t)(rowbase + er) * HH + (hbase + eu)] = h_last;
    }

    // ---- publish arrival ----
    if (t < TT - 1) {
      asm volatile("s_waitcnt vmcnt(0)" ::: "memory");   // h stores at coherence point
      __syncthreads();
      if (tid == 0) __hip_atomic_fetch_add(cnt, 1u, __ATOMIC_RELAXED, __HIP_MEMORY_SCOPE_AGENT);
    }
  }

  // ---- final h, c outputs ----
  {
    const size_t ob = (size_t)TT * (BB * HH) + (size_t)(rowbase + er) * HH + (hbase + eu);
    out[ob] = h_last;
    out[ob + (size_t)BB * HH] = c_reg;
  }
}

extern "C" void kernel_launch(void* const* d_in, const int* in_sizes, int n_in,
                              void* d_out, int out_size, void* d_ws, size_t ws_size,
                              hipStream_t stream) {
  const float* x    = (const float*)d_in[0];
  const float* W_ih = (const float*)d_in[1];
  const float* b_ih = (const float*)d_in[2];
  const float* W_hh = (const float*)d_in[3];
  const float* b_hh = (const float*)d_in[4];
  float* out = (float*)d_out;

  unsigned short* h_buf   = (unsigned short*)d_ws;                    // 262144 B
  unsigned int*   counters = (unsigned int*)((char*)d_ws + 262144);   // 1024 B

  // zero h double-buffer + counters (ws is poisoned before every launch)
  lstm_init<<<dim3(257), dim3(256), 0, stream>>>((unsigned int*)d_ws);

  lstm_persist<<<dim3(256), dim3(256), 0, stream>>>(
      x, W_ih, b_ih, W_hh, b_hh, out, h_buf, counters);
}

// Round 2
// 4068.925 us; speedup vs baseline: 3.0774x; 3.0774x over previous
//
#include <hip/hip_runtime.h>

#define TT 1024
#define BB 128
#define HH 512
#define NWGG 16u   // WGs per batch-group (sync participants)

typedef __bf16  bf16x8 __attribute__((ext_vector_type(8)));
typedef float   f32x4  __attribute__((ext_vector_type(4)));
typedef float   f32x8  __attribute__((ext_vector_type(8)));
typedef unsigned long long u64;

static __device__ __forceinline__ bf16x8 cvt8(const float* __restrict__ p) {
  f32x8 f = *(const f32x8*)p;
  return __builtin_convertvector(f, bf16x8);
}

// Zero h double-buffer (2*128*512 bf16 = 256 KiB) + barrier lines (2 KiB).
// 258 * 256 * 4 B = 264192 B exactly.
__global__ void lstm_init(unsigned int* __restrict__ buf) {
  buf[blockIdx.x * 256u + threadIdx.x] = 0u;
}

// 128 WGs = 8 batch-groups (16 rows) x 16 hidden-slices (32 units).
// 512 threads = 8 waves; wave w: gate g=w&3, unit-half hb=w>>2.
__global__ __launch_bounds__(512, 2) void lstm_persist(
    const float* __restrict__ x,      // (T,B,512) fp32
    const float* __restrict__ W_ih,   // (2048,512) fp32
    const float* __restrict__ b_ih,
    const float* __restrict__ W_hh,   // (2048,512) fp32
    const float* __restrict__ b_hh,
    float* __restrict__ out,          // T*B*H ++ h ++ c
    unsigned short* __restrict__ h_buf,   // ws: 2 x 128x512 bf16
    unsigned int* __restrict__ counters)  // ws: per group {arrive | flag} lines
{
  const int wg = blockIdx.x;       // 0..127
  const int bg = wg & 7;           // batch group (round-robin -> XCD locality, perf only)
  const int ng = wg >> 3;          // hidden slice 0..15
  const int rowbase = bg << 4;
  const int ubase = ng << 5;       // 32 units per WG
  const int tid = threadIdx.x;
  const int wave = tid >> 6;
  const int g  = wave & 3;         // gate: 0=i 1=f 2=o 3=g
  const int hb = wave >> 2;        // 0..1
  const int lane = tid & 63;
  const int fr = lane & 15;
  const int kl = (lane >> 4) << 3;

  __shared__ __align__(16) unsigned char xsm[2][16384]; // x tile bf16, dbuf, swizzled
  __shared__ __align__(16) unsigned char hsm[16384];    // h tile bf16, swizzled
  __shared__ float zbuf[4][16][33];

  // ---- weights into registers (once) ----
  bf16x8 Bx[16], Bh[16];
  const int gcol = (g << 9) + ubase + (hb << 4) + fr;   // 0..2047
  {
    const float* wi = W_ih + (size_t)gcol * 512 + kl;
    const float* wh = W_hh + (size_t)gcol * 512 + kl;
#pragma unroll
    for (int kk = 0; kk < 16; ++kk) {
      Bx[kk] = cvt8(wi + kk * 32);
      Bh[kk] = cvt8(wh + kk * 32);
    }
  }
  const float bias_l = b_ih[gcol] + b_hh[gcol];

  unsigned int* arrive = counters + (bg << 6);   // 256 B per group
  unsigned int* flag   = arrive + 32;            // separate 128-B line

  const int er = tid >> 5;     // epilogue row 0..15
  const int eu = tid & 31;     // epilogue unit 0..31
  const int srow = tid >> 5;   // staging row
  const int sj   = tid & 31;
  const int swz  = (srow & 7) << 4;

  float c_reg = 0.f, h_last = 0.f;

  // ---- prologue: stage x(0) into xsm[0] ----
  {
    const float* xp = x + ((size_t)rowbase + srow) * HH + sj * 16;
    bf16x8 v0 = cvt8(xp);
    bf16x8 v1 = cvt8(xp + 8);
    const int byte = (srow << 10) + (sj << 5);
    *(bf16x8*)(xsm[0] + ( byte       ^ swz)) = v0;
    *(bf16x8*)(xsm[0] + ((byte + 16) ^ swz)) = v1;
  }

#pragma clang loop unroll(disable)
  for (int t = 0; t < TT; ++t) {
    // ---- wait for h(t-1): poll read-only flag line ----
    if (t > 0) {
      if (tid == 0) {
        while (__hip_atomic_load(flag, __ATOMIC_RELAXED, __HIP_MEMORY_SCOPE_AGENT)
               < (unsigned)t) { }
      }
    }
    __syncthreads();   // spin done; xsm[t&1] (staged prev iter) ready

    // ---- issue h(t-1) stage loads (MALL) ----
    u64 hq[4];
    {
      const u64* hrow = (const u64*)(h_buf + (size_t)(t & 1) * (BB * HH)
                                           + (size_t)(rowbase + srow) * HH);
#pragma unroll
      for (int i = 0; i < 4; ++i)
        hq[i] = __hip_atomic_load(hrow + sj + (i << 5),
                                  __ATOMIC_RELAXED, __HIP_MEMORY_SCOPE_AGENT);
    }
    // ---- issue x(t+1) loads (hide HBM latency under this whole iter) ----
    f32x8 xv0, xv1;
    const bool havnext = (t + 1 < TT);
    if (havnext) {
      const float* xp = x + (((size_t)(t + 1)) * BB + rowbase + srow) * HH + sj * 16;
      xv0 = *(const f32x8*)xp;
      xv1 = *(const f32x8*)(xp + 8);
    }

    // ---- x MFMAs from xsm[t&1] (overlap h-load latency) ----
    f32x4 acc0 = {0,0,0,0}, acc1 = {0,0,0,0}, acc2 = {0,0,0,0}, acc3 = {0,0,0,0};
    {
      const unsigned char* xb = xsm[t & 1];
#pragma unroll
      for (int kk = 0; kk < 16; ++kk) {
        int byte = (fr << 10) + ((kk * 32 + kl) << 1);
        byte ^= (fr & 7) << 4;
        bf16x8 a = *(const bf16x8*)(xb + byte);
        if (kk & 1) acc1 = __builtin_amdgcn_mfma_f32_16x16x32_bf16(a, Bx[kk], acc1, 0, 0, 0);
        else        acc0 = __builtin_amdgcn_mfma_f32_16x16x32_bf16(a, Bx[kk], acc0, 0, 0, 0);
      }
    }

    // ---- write h tile + x(t+1) tile to LDS ----
    {
      const int b0 = (srow << 10);
#pragma unroll
      for (int i = 0; i < 4; ++i) {
        const int byte = b0 + ((sj + (i << 5)) << 3);
        *(u64*)(hsm + (byte ^ swz)) = hq[i];
      }
      if (havnext) {
        bf16x8 v0 = __builtin_convertvector(xv0, bf16x8);
        bf16x8 v1 = __builtin_convertvector(xv1, bf16x8);
        const int xbyte = b0 + (sj << 5);
        unsigned char* xb = xsm[(t + 1) & 1];
        *(bf16x8*)(xb + ( xbyte       ^ swz)) = v0;
        *(bf16x8*)(xb + ((xbyte + 16) ^ swz)) = v1;
      }
    }
    __syncthreads();

    // ---- h MFMAs ----
#pragma unroll
    for (int kk = 0; kk < 16; ++kk) {
      int byte = (fr << 10) + ((kk * 32 + kl) << 1);
      byte ^= (fr & 7) << 4;
      bf16x8 a = *(const bf16x8*)(hsm + byte);
      if (kk & 1) acc3 = __builtin_amdgcn_mfma_f32_16x16x32_bf16(a, Bh[kk], acc3, 0, 0, 0);
      else        acc2 = __builtin_amdgcn_mfma_f32_16x16x32_bf16(a, Bh[kk], acc2, 0, 0, 0);
    }

    // ---- z exchange (C/D layout: col=lane&15, row=(lane>>4)*4+r) ----
    {
      f32x4 z = acc0 + acc1 + acc2 + acc3;
      const int r0 = (lane >> 4) << 2;
      const int u = (hb << 4) + fr;
#pragma unroll
      for (int r = 0; r < 4; ++r) zbuf[g][r0 + r][u] = z[r] + bias_l;
    }
    __syncthreads();

    // ---- gates + state update ----
    {
      const float iz = zbuf[0][er][eu];
      const float fz = zbuf[1][er][eu];
      const float oz = zbuf[2][er][eu];
      const float gz = zbuf[3][er][eu];
      const float ig = 1.f / (1.f + __expf(-iz));
      const float fg = 1.f / (1.f + __expf(-fz));
      const float og = 1.f / (1.f + __expf(-oz));
      const float e2g = __expf(2.f * gz);
      const float gg = 1.f - 2.f / (e2g + 1.f);   // tanh
      c_reg = fg * c_reg + ig * gg;
      const float e2c = __expf(2.f * c_reg);
      const float tc = 1.f - 2.f / (e2c + 1.f);
      h_last = og * tc;

      const unsigned short hv = __builtin_bit_cast(unsigned short, (__bf16)h_last);
      __hip_atomic_store(h_buf + (size_t)((t + 1) & 1) * (BB * HH)
                               + (size_t)(rowbase + er) * HH + (ubase + eu),
                         hv, __ATOMIC_RELAXED, __HIP_MEMORY_SCOPE_AGENT);
    }

    // ---- publish: drain h stores only, then arrive; last arriver sets flag ----
    if (t < TT - 1) {
      asm volatile("s_waitcnt vmcnt(0)" ::: "memory");
      __syncthreads();
      if (tid == 0) {
        const unsigned old = __hip_atomic_fetch_add(arrive, 1u, __ATOMIC_RELAXED,
                                                    __HIP_MEMORY_SCOPE_AGENT);
        if (old == NWGG * (unsigned)(t + 1) - 1u)
          __hip_atomic_store(flag, (unsigned)(t + 1), __ATOMIC_RELAXED,
                             __HIP_MEMORY_SCOPE_AGENT);
      }
    }

    // ---- out store (off critical path) ----
    out[(size_t)t * (BB * HH) + (size_t)(rowbase + er) * HH + (ubase + eu)] = h_last;
  }

  // ---- final h, c ----
  {
    const size_t ob = (size_t)TT * (BB * HH) + (size_t)(rowbase + er) * HH + (ubase + eu);
    out[ob] = h_last;
    out[ob + (size_t)BB * HH] = c_reg;
  }
}

extern "C" void kernel_launch(void* const* d_in, const int* in_sizes, int n_in,
                              void* d_out, int out_size, void* d_ws, size_t ws_size,
                              hipStream_t stream) {
  const float* x    = (const float*)d_in[0];
  const float* W_ih = (const float*)d_in[1];
  const float* b_ih = (const float*)d_in[2];
  const float* W_hh = (const float*)d_in[3];
  const float* b_hh = (const float*)d_in[4];
  float* out = (float*)d_out;

  unsigned short* h_buf    = (unsigned short*)d_ws;                   // 262144 B
  unsigned int*   counters = (unsigned int*)((char*)d_ws + 262144);   // 2048 B

  lstm_init<<<dim3(258), dim3(256), 0, stream>>>((unsigned int*)d_ws);

  lstm_persist<<<dim3(128), dim3(512), 0, stream>>>(
      x, W_ih, b_ih, W_hh, b_hh, out, h_buf, counters);
}